// Round 3
// baseline (555.923 us; speedup 1.0000x reference)
//
#include <hip/hip_runtime.h>
#include <cstdint>

#define BB 8
#define CC 128
#define HH 96
#define WW 160
#define HWsz (HH * WW)          // 15360
#define TH 8
#define TW 32
#define CSTEP 8
#define HALO_H (TH + 8)         // 16
#define HALO_W (TW + 8)         // 40
#define CH_WORDS (HALO_H * HALO_W)       // 640
#define CHUNK_WORDS (CSTEP * CH_WORDS)   // 5120 words = 20 KB
#define NWAVES 9
#define NTHREADS (NWAVES * 64)           // 576
#define WLOADS (CHUNK_WORDS / 64)        // 80 wave-sized dword loads per chunk
#define NCHUNKS (CC / CSTEP)             // 16
#define NBLOCKS (BB * (HH / TH) * (WW / TW))  // 480

__device__ __forceinline__ void g2l_dword(const float* g, float* l) {
  __builtin_amdgcn_global_load_lds((const __attribute__((address_space(1))) void*)g,
                                   (__attribute__((address_space(3))) void*)l,
                                   4, 0, 0);
}

// Straight-line macros (NO lambdas: R2 showed by-ref lambda captures defeat
// SROA -> acc spills to scratch -> 900 MB of HBM scratch traffic).
#define STAGE(chunk, buf) do {                                          \
    const float* _src = x2b + (size_t)(chunk) * (CSTEP * HWsz);         \
    _Pragma("unroll")                                                   \
    for (int _i = 0; _i < 9; ++_i) {                                    \
      const int _idx = wv + 9 * _i;                                     \
      if (_idx < WLOADS) /* wave-uniform */                             \
        g2l_dword(_src + soff[_i], (buf) + _idx * 64);                  \
    }                                                                   \
  } while (0)

#define COMPUTE(chunk, buf) do {                                        \
    _Pragma("unroll")                                                   \
    for (int _ci = 0; _ci < CSTEP; ++_ci) {                             \
      const float4 _a4 = *(const float4*)(x1b + (size_t)((chunk) * CSTEP + _ci) * HWsz); \
      const float _av[4] = {_a4.x, _a4.y, _a4.z, _a4.w};                \
      const float4* _wr = (const float4*)((buf) + _ci * CH_WORDS + rowbase); \
      const float4 _f0 = _wr[0];                                        \
      const float4 _f1 = _wr[1];                                        \
      const float4 _f2 = _wr[2];                                        \
      const float _w12[12] = {_f0.x, _f0.y, _f0.z, _f0.w,               \
                              _f1.x, _f1.y, _f1.z, _f1.w,               \
                              _f2.x, _f2.y, _f2.z, _f2.w};              \
      _Pragma("unroll")                                                 \
      for (int _dx = 0; _dx < 9; ++_dx)                                 \
        _Pragma("unroll")                                               \
        for (int _p = 0; _p < 4; ++_p)                                  \
          acc[_dx][_p] = fmaf(_av[_p], _w12[_dx + _p], acc[_dx][_p]);   \
    }                                                                   \
  } while (0)

extern "C" __global__ void __launch_bounds__(NTHREADS, 4)
corr81_kernel(const float* __restrict__ x1, const float* __restrict__ x2,
              float* __restrict__ out)
{
  // Two DISTINCT shared objects -> compiler can tell ds_read(A) doesn't alias
  // the in-flight global_load_lds writes into B.
  __shared__ __align__(16) float ldsA[CHUNK_WORDS];
  __shared__ __align__(16) float ldsB[CHUNK_WORDS];

  const int tid  = threadIdx.x;
  const int wv   = tid >> 6;     // dy index 0..8 (wave-uniform)
  const int lane = tid & 63;
  const int r    = lane >> 3;    // tile row 0..7
  const int j    = lane & 7;     // w-slot 0..7 (4 px each)

  const int bid = blockIdx.x;
  const int wt  = bid % (WW / TW);
  const int ht  = (bid / (WW / TW)) % (HH / TH);
  const int b   = bid / ((WW / TW) * (HH / TH));
  const int h0  = ht * TH;
  const int w0  = wt * TW;

  // Per-lane x2 staging offsets (word offsets, chunk-invariant; replicate-pad
  // clamping folded in). Identical to the verified round-1 scheme.
  uint32_t soff[9];
#pragma unroll
  for (int i = 0; i < 9; ++i) {
    const int idx = wv + 9 * i;          // wave-load slot 0..80
    const int e   = idx * 64 + lane;     // LDS word this lane fills
    const int ci  = e / CH_WORDS;        // channel within chunk
    const int rem = e - ci * CH_WORDS;
    const int hr  = rem / HALO_W;        // halo row 0..15
    const int wh  = rem - hr * HALO_W;   // halo col 0..39
    int gh = h0 + hr - 4; gh = gh < 0 ? 0 : (gh > HH - 1 ? HH - 1 : gh);
    int gw = w0 + wh - 4; gw = gw < 0 ? 0 : (gw > WW - 1 ? WW - 1 : gw);
    soff[i] = (uint32_t)((ci * HH + gh) * WW + gw);
  }

  const float* x2b = x2 + (size_t)b * CC * HWsz;
  const float* x1b = x1 + (size_t)b * CC * HWsz + (size_t)(h0 + r) * WW + (w0 + 4 * j);

  float acc[9][4];
#pragma unroll
  for (int dx = 0; dx < 9; ++dx)
#pragma unroll
    for (int p = 0; p < 4; ++p) acc[dx][p] = 0.f;

  const int rowbase = (r + wv) * HALO_W + 4 * j;

  // Software pipeline: prefetch chunk k+1 BEFORE compute(k); the barrier's
  // vmcnt(0) drain then lands after ~compute-duration of latency hiding.
  STAGE(0, ldsA);
  __syncthreads();
#pragma unroll 1
  for (int chunk = 0; chunk < NCHUNKS; chunk += 2) {
    STAGE(chunk + 1, ldsB);            // NCHUNKS even -> chunk+1 always valid
    COMPUTE(chunk, ldsA);
    __syncthreads();
    if (chunk + 2 < NCHUNKS) STAGE(chunk + 2, ldsA);
    COMPUTE(chunk + 1, ldsB);
    __syncthreads();
  }

  // epilogue: out[((b*81 + wv*9+dx)*H + h0+r)*W + w0+4j ...], scale 1/8
  float* op = out + (((size_t)b * 81 + (size_t)wv * 9) * HH + (h0 + r)) * WW + (w0 + 4 * j);
#pragma unroll
  for (int dx = 0; dx < 9; ++dx) {
    float4 v;
    v.x = acc[dx][0] * 0.125f;
    v.y = acc[dx][1] * 0.125f;
    v.z = acc[dx][2] * 0.125f;
    v.w = acc[dx][3] * 0.125f;
    *(float4*)(op + (size_t)dx * HWsz) = v;
  }
}

extern "C" void kernel_launch(void* const* d_in, const int* in_sizes, int n_in,
                              void* d_out, int out_size, void* d_ws, size_t ws_size,
                              hipStream_t stream) {
  const float* x1 = (const float*)d_in[0];
  const float* x2 = (const float*)d_in[1];
  float* out = (float*)d_out;
  corr81_kernel<<<dim3(NBLOCKS), dim3(NTHREADS), 0, stream>>>(x1, x2, out);
}

// Round 4
// 211.805 us; speedup vs baseline: 2.6247x; 2.6247x over previous
//
#include <hip/hip_runtime.h>
#include <cstdint>

#define BB 8
#define CC 128
#define HH 96
#define WW 160
#define HWsz (HH * WW)          // 15360
#define TH 8
#define TW 32
#define CSTEP 8
#define HALO_H (TH + 8)         // 16
#define HALO_W (TW + 8)         // 40
#define CH_WORDS (HALO_H * HALO_W)       // 640
#define CHUNK_WORDS (CSTEP * CH_WORDS)   // 5120 words = 20 KB per buffer
#define NWAVES 9
#define NTHREADS (NWAVES * 64)           // 576
#define WLOADS (CHUNK_WORDS / 64)        // 80 wave-sized dword loads per chunk
#define NCHUNKS (CC / CSTEP)             // 16
#define NBLOCKS (BB * (HH / TH) * (WW / TW))  // 480

__device__ __forceinline__ void g2l_dword(const float* g, float* l) {
  __builtin_amdgcn_global_load_lds((const __attribute__((address_space(1))) void*)g,
                                   (__attribute__((address_space(3))) void*)l,
                                   4, 0, 0);
}

// launch_bounds(576,2): VGPR cap ~113. R2/R3 showed that pressuring the
// allocator (double compute body) spills acc[9][4] to scratch -> ~800 MB of
// HBM RMW traffic. Keep ONE stage + ONE compute per iteration, rolled.
extern "C" __global__ void __launch_bounds__(NTHREADS, 2)
corr81_kernel(const float* __restrict__ x1, const float* __restrict__ x2,
              float* __restrict__ out)
{
  __shared__ __align__(16) float lds[2][CHUNK_WORDS];  // ping-pong, 40 KB

  const int tid  = threadIdx.x;
  const int wv   = tid >> 6;     // dy index 0..8 (wave-uniform)
  const int lane = tid & 63;
  const int r    = lane >> 3;    // tile row 0..7
  const int j    = lane & 7;     // w-slot 0..7 (4 px each)

  const int bid = blockIdx.x;
  const int wt  = bid % (WW / TW);
  const int ht  = (bid / (WW / TW)) % (HH / TH);
  const int b   = bid / ((WW / TW) * (HH / TH));
  const int h0  = ht * TH;
  const int w0  = wt * TW;

  // Per-lane x2 staging offsets (word offsets, chunk-invariant; replicate-pad
  // clamping folded in). Identical to the verified round-1 scheme.
  uint32_t soff[9];
#pragma unroll
  for (int i = 0; i < 9; ++i) {
    const int idx = wv + 9 * i;          // wave-load slot 0..80
    const int e   = idx * 64 + lane;     // LDS word this lane fills
    const int ci  = e / CH_WORDS;        // channel within chunk
    const int rem = e - ci * CH_WORDS;
    const int hr  = rem / HALO_W;        // halo row 0..15
    const int wh  = rem - hr * HALO_W;   // halo col 0..39
    int gh = h0 + hr - 4; gh = gh < 0 ? 0 : (gh > HH - 1 ? HH - 1 : gh);
    int gw = w0 + wh - 4; gw = gw < 0 ? 0 : (gw > WW - 1 ? WW - 1 : gw);
    soff[i] = (uint32_t)((ci * HH + gh) * WW + gw);
  }

  const float* x2b = x2 + (size_t)b * CC * HWsz;
  const float* x1b = x1 + (size_t)b * CC * HWsz + (size_t)(h0 + r) * WW + (w0 + 4 * j);

  float acc[9][4];
#pragma unroll
  for (int dx = 0; dx < 9; ++dx)
#pragma unroll
    for (int p = 0; p < 4; ++p) acc[dx][p] = 0.f;

  const int rowbase = (r + wv) * HALO_W + 4 * j;

  // ---- prologue: stage chunk 0 into buffer 0
  {
    const float* src = x2b;  // chunk 0
#pragma unroll
    for (int i = 0; i < 9; ++i) {
      const int idx = wv + 9 * i;
      if (idx < WLOADS)                       // wave-uniform
        g2l_dword(src + soff[i], &lds[0][idx * 64]);
    }
  }
  __syncthreads();

  // ---- rolled ping-pong: stage(k+1) issued BEFORE compute(k); the single
  // barrier's vmcnt(0) drain is covered by compute's ~600+ cycles of work.
#pragma unroll 1
  for (int chunk = 0; chunk < NCHUNKS; ++chunk) {
    const int cb = chunk & 1;        // compute buffer
    const int sb = cb ^ 1;           // stage buffer

    if (chunk + 1 < NCHUNKS) {
      const float* src = x2b + (size_t)(chunk + 1) * (CSTEP * HWsz);
#pragma unroll
      for (int i = 0; i < 9; ++i) {
        const int idx = wv + 9 * i;
        if (idx < WLOADS)
          g2l_dword(src + soff[i], &lds[sb][idx * 64]);
      }
    }

#pragma unroll
    for (int ci = 0; ci < CSTEP; ++ci) {
      const float4 a4 = *(const float4*)(x1b + (size_t)(chunk * CSTEP + ci) * HWsz);
      const float av[4] = {a4.x, a4.y, a4.z, a4.w};
      const float4* wr = (const float4*)&lds[cb][ci * CH_WORDS + rowbase];
      const float4 f0 = wr[0];
      const float4 f1 = wr[1];
      const float4 f2 = wr[2];
      const float w12[12] = {f0.x, f0.y, f0.z, f0.w,
                             f1.x, f1.y, f1.z, f1.w,
                             f2.x, f2.y, f2.z, f2.w};
#pragma unroll
      for (int dx = 0; dx < 9; ++dx)
#pragma unroll
        for (int p = 0; p < 4; ++p)
          acc[dx][p] = fmaf(av[p], w12[dx + p], acc[dx][p]);
    }

    __syncthreads();   // one barrier per chunk (R1 had two)
  }

  // epilogue: out[((b*81 + wv*9+dx)*H + h0+r)*W + w0+4j ...], scale 1/8
  float* op = out + (((size_t)b * 81 + (size_t)wv * 9) * HH + (h0 + r)) * WW + (w0 + 4 * j);
#pragma unroll
  for (int dx = 0; dx < 9; ++dx) {
    float4 v;
    v.x = acc[dx][0] * 0.125f;
    v.y = acc[dx][1] * 0.125f;
    v.z = acc[dx][2] * 0.125f;
    v.w = acc[dx][3] * 0.125f;
    *(float4*)(op + (size_t)dx * HWsz) = v;
  }
}

extern "C" void kernel_launch(void* const* d_in, const int* in_sizes, int n_in,
                              void* d_out, int out_size, void* d_ws, size_t ws_size,
                              hipStream_t stream) {
  const float* x1 = (const float*)d_in[0];
  const float* x2 = (const float*)d_in[1];
  float* out = (float*)d_out;
  corr81_kernel<<<dim3(NBLOCKS), dim3(NTHREADS), 0, stream>>>(x1, x2, out);
}